// Round 4
// baseline (188.456 us; speedup 1.0000x reference)
//
#include <hip/hip_runtime.h>
#include <math.h>

#define DEG 32
#define NHO 64   // HEADS*OUT_F = 4*16
#define NPW 4    // nodes per wave in gat_kernel
#define NPB 16   // nodes per block (4 waves * NPW)

// DPP butterfly add within rows of 16 lanes (one attention head).
// xor1 = quad_perm[1,0,3,2]=0xB1, xor2 = quad_perm[2,3,0,1]=0x4E,
// then row_half_mirror(0x141) == xor4 (quads already uniform),
// row_mirror(0x140) == xor8 (halves already uniform).
template <int CTRL>
__device__ __forceinline__ float dpp_add(float v) {
    int t = __builtin_amdgcn_update_dpp(0, __float_as_int(v), CTRL, 0xF, 0xF, true);
    return v + __int_as_float(t);
}

__device__ __forceinline__ unsigned bf16_rne(float f) {
    unsigned u = __float_as_uint(f);
    return (u + 0x7fffu + ((u >> 16) & 1u)) >> 16;
}

// ---------------------------------------------------------------------------
// Projection, fp32 output (Pq): thread = node, weights are wave-uniform ->
// scalar (SGPR) loads feeding v_fma's constant operand. No LDS. 64-thr
// blocks spread 782 blocks over 256 CUs.
// ---------------------------------------------------------------------------
__global__ __launch_bounds__(64) void proj_q_kernel(
    const float* __restrict__ Q,
    const float* __restrict__ W,
    float* __restrict__ P,
    int N)
{
    int n = blockIdx.x * 64 + threadIdx.x;
    bool act = (n < N);

    float q[64];
#pragma unroll
    for (int i = 0; i < 64; i++)
        q[i] = act ? Q[(size_t)i * N + n] : 0.f;   // coalesced per i

    for (int l4 = 0; l4 < 16; l4++) {
        const float* w0 = W + (size_t)(l4 * 4 + 0) * 64;  // wave-uniform rows
        const float* w1 = W + (size_t)(l4 * 4 + 1) * 64;
        const float* w2 = W + (size_t)(l4 * 4 + 2) * 64;
        const float* w3 = W + (size_t)(l4 * 4 + 3) * 64;
        float a0 = 0.f, a1 = 0.f, a2 = 0.f, a3 = 0.f;
#pragma unroll
        for (int i = 0; i < 64; i++) {
            float qi = q[i];
            a0 = fmaf(w0[i], qi, a0);
            a1 = fmaf(w1[i], qi, a1);
            a2 = fmaf(w2[i], qi, a2);
            a3 = fmaf(w3[i], qi, a3);
        }
        if (act)
            *(float4*)(P + (size_t)n * NHO + l4 * 4) = make_float4(a0, a1, a2, a3);
    }
}

// ---------------------------------------------------------------------------
// Projection, bf16 output (Pk table): same structure, packs 4 outputs into
// 8 B. Table shrinks to 6.4 MB so gat's random gathers stay L2-resident.
// ---------------------------------------------------------------------------
__global__ __launch_bounds__(64) void proj_k_kernel(
    const float* __restrict__ Q,
    const float* __restrict__ W,
    unsigned short* __restrict__ Pkb,
    int N)
{
    int n = blockIdx.x * 64 + threadIdx.x;
    bool act = (n < N);

    float q[64];
#pragma unroll
    for (int i = 0; i < 64; i++)
        q[i] = act ? Q[(size_t)i * N + n] : 0.f;

    for (int l4 = 0; l4 < 16; l4++) {
        const float* w0 = W + (size_t)(l4 * 4 + 0) * 64;
        const float* w1 = W + (size_t)(l4 * 4 + 1) * 64;
        const float* w2 = W + (size_t)(l4 * 4 + 2) * 64;
        const float* w3 = W + (size_t)(l4 * 4 + 3) * 64;
        float a0 = 0.f, a1 = 0.f, a2 = 0.f, a3 = 0.f;
#pragma unroll
        for (int i = 0; i < 64; i++) {
            float qi = q[i];
            a0 = fmaf(w0[i], qi, a0);
            a1 = fmaf(w1[i], qi, a1);
            a2 = fmaf(w2[i], qi, a2);
            a3 = fmaf(w3[i], qi, a3);
        }
        if (act) {
            uint2 pk;
            pk.x = bf16_rne(a0) | (bf16_rne(a1) << 16);
            pk.y = bf16_rne(a2) | (bf16_rne(a3) << 16);
            *(uint2*)((char*)Pkb + (size_t)n * 128 + l4 * 8) = pk;
        }
    }
}

// ---------------------------------------------------------------------------
// GAT: one wave handles NPW nodes, lane = h*16+o. Full 32-deep gather
// prefetch (bf16 table: 2 B/lane, 128 B/row). Fixed-max softmax in exp2
// domain. Per-edge logit via a*lrelu(x) = c1*x + c2*|x| (abs = free
// operand modifier), c1*x folded into fma(c1, kv, c1*qv).
// ---------------------------------------------------------------------------
__global__ __launch_bounds__(256) void gat_kernel(
    const int*            __restrict__ adj,   // [N][DEG]
    const float*          __restrict__ Pq,    // [N][64] fp32
    const unsigned short* __restrict__ Pkb,   // [N][64] bf16
    const float*          __restrict__ aw,    // [64]
    float*                __restrict__ out,   // [64][N]
    int N)
{
    __shared__ float tile[NHO][NPB + 1];

    int lane = threadIdx.x & 63;
    int wv   = threadIdx.x >> 6;

    float a2l = aw[lane] * 1.44269504f;   // fold log2(e)
    float c1  = 0.505f * a2l;
    float c2  = 0.495f * a2l;

    int nbase = blockIdx.x * NPB + wv * NPW;

#pragma unroll 1
    for (int ni = 0; ni < NPW; ni++) {
        int n = nbase + ni;
        float r = 0.f;
        if (n < N) {
            float qv  = Pq[(size_t)n * NHO + lane];
            int jreg  = (lane < DEG) ? adj[(size_t)n * DEG + lane] : -1;
            float c1q = c1 * qv;

            unsigned short raw[DEG];
            int jv[DEG];
#pragma unroll
            for (int t = 0; t < DEG; t++) {
                int j = __builtin_amdgcn_readlane(jreg, t);   // SGPR, uniform
                jv[t] = j;
                const unsigned short* row =
                    Pkb + (((size_t)(j < 0 ? 0 : j)) << 6);
                raw[t] = row[lane];   // coalesced 128B bf16 gather
            }

            float s = 0.f, acc = 0.f;
#pragma unroll
            for (int t = 0; t < DEG; t++) {
                float kv = __uint_as_float((unsigned)raw[t] << 16);  // bf16->f32
                float x  = qv + kv;
                float tt = fmaf(c1, kv, c1q);          // c1*(qv+kv)
                float c  = fmaf(c2, fabsf(x), tt);     // a2*lrelu(x)
                c = dpp_add<0xB1>(c);     // xor 1
                c = dpp_add<0x4E>(c);     // xor 2
                c = dpp_add<0x141>(c);    // xor 4 (half-mirror)
                c = dpp_add<0x140>(c);    // xor 8 (mirror)
                float lg = (jv[t] >= 0) ? c : -1e30f;
                float p  = __builtin_amdgcn_exp2f(lg); // raw v_exp_f32
                s   += p;
                acc  = fmaf(p, kv, acc);
            }
            // s==0 only when every neighbor is padded -> reference outputs 0
            r = (s > 0.f) ? acc * __builtin_amdgcn_rcpf(s) : 0.f;
        }
        tile[lane][wv * NPW + ni] = r;
    }
    __syncthreads();

    // coalesced write-out: 64 rows x 16 cols, one float4 per thread
    int n0 = blockIdx.x * NPB;
    int l  = threadIdx.x >> 2;
    int c4 = threadIdx.x & 3;
    int nc = n0 + c4 * 4;
    float4 v = make_float4(tile[l][c4 * 4 + 0], tile[l][c4 * 4 + 1],
                           tile[l][c4 * 4 + 2], tile[l][c4 * 4 + 3]);
    if (nc + 3 < N) {
        *(float4*)(out + (size_t)l * N + nc) = v;
    } else {
#pragma unroll
        for (int e = 0; e < 4; e++)
            if (nc + e < N) out[(size_t)l * N + nc + e] = (&v.x)[e];
    }
}

extern "C" void kernel_launch(void* const* d_in, const int* in_sizes, int n_in,
                              void* d_out, int out_size, void* d_ws, size_t ws_size,
                              hipStream_t stream) {
    const int*   adj = (const int*)  d_in[0];
    const float* Q   = (const float*)d_in[1];
    const float* qw  = (const float*)d_in[2];
    const float* kw  = (const float*)d_in[3];
    const float* aw  = (const float*)d_in[4];
    float*       out = (float*)d_out;

    int N = in_sizes[0] / DEG;  // 50000

    float*          Pq  = (float*)d_ws;                       // [N][64] fp32
    unsigned short* Pkb = (unsigned short*)(Pq + (size_t)N * NHO);  // [N][64] bf16

    int pblocks = (N + 63) / 64;
    proj_q_kernel<<<pblocks, 64, 0, stream>>>(Q, qw, Pq, N);
    proj_k_kernel<<<pblocks, 64, 0, stream>>>(Q, kw, Pkb, N);

    gat_kernel<<<(N + NPB - 1) / NPB, 256, 0, stream>>>(adj, Pq, Pkb, aw, out, N);
}

// Round 5
// 153.592 us; speedup vs baseline: 1.2270x; 1.2270x over previous
//
#include <hip/hip_runtime.h>
#include <math.h>

#define DEG 32
#define NHO 64   // HEADS*OUT_F = 4*16
#define NPW 4    // nodes per wave in gat_kernel
#define NPB 16   // nodes per block (4 waves * NPW)

// DPP butterfly add within rows of 16 lanes (one attention head).
template <int CTRL>
__device__ __forceinline__ float dpp_add(float v) {
    int t = __builtin_amdgcn_update_dpp(0, __float_as_int(v), CTRL, 0xF, 0xF, true);
    return v + __int_as_float(t);
}

__device__ __forceinline__ unsigned bf16_rne(float f) {
    unsigned u = __float_as_uint(f);
    return (u + 0x7fffu + ((u >> 16) & 1u)) >> 16;
}

// ---------------------------------------------------------------------------
// Fused projection. blockIdx.y in [0,4): bit1 = which projection (0 -> Pq
// fp32, 1 -> Pk bf16), bit0 = which half of the 64 output rows. Each block:
// 256 nodes x 32 outputs. Thread = node; q[64] in VGPRs (coalesced loads);
// weight rows are wave-uniform -> s_load feeding v_fma's SGPR operand.
// 784 blocks / 3136 waves (~3 per SIMD) so latency is hidden, vs R4's 0.76.
// ---------------------------------------------------------------------------
__global__ __launch_bounds__(256) void proj_kernel(
    const float* __restrict__ Q,
    const float* __restrict__ Wq,
    const float* __restrict__ Wk,
    float* __restrict__ Pq,
    unsigned short* __restrict__ Pkb,
    int N)
{
    const int kproj = (blockIdx.y >> 1);   // 0: query, 1: key
    const int half  = (blockIdx.y & 1);    // output rows [half*32, half*32+32)
    const float* W  = (kproj ? Wk : Wq) + (size_t)half * 32 * 64;

    int n = blockIdx.x * 256 + threadIdx.x;
    bool act = (n < N);

    float q[64];
#pragma unroll
    for (int i = 0; i < 64; i++)
        q[i] = act ? Q[(size_t)i * N + n] : 0.f;   // coalesced per i

    for (int l4 = 0; l4 < 8; l4++) {
        const float* w0 = W + (size_t)(l4 * 4 + 0) * 64;  // wave-uniform rows
        const float* w1 = W + (size_t)(l4 * 4 + 1) * 64;
        const float* w2 = W + (size_t)(l4 * 4 + 2) * 64;
        const float* w3 = W + (size_t)(l4 * 4 + 3) * 64;
        float a0 = 0.f, a1 = 0.f, a2 = 0.f, a3 = 0.f;
#pragma unroll
        for (int i = 0; i < 64; i++) {
            float qi = q[i];
            a0 = fmaf(w0[i], qi, a0);
            a1 = fmaf(w1[i], qi, a1);
            a2 = fmaf(w2[i], qi, a2);
            a3 = fmaf(w3[i], qi, a3);
        }
        if (act) {
            if (kproj == 0) {
                *(float4*)(Pq + (size_t)n * NHO + half * 32 + l4 * 4) =
                    make_float4(a0, a1, a2, a3);
            } else {
                uint2 pk;
                pk.x = bf16_rne(a0) | (bf16_rne(a1) << 16);
                pk.y = bf16_rne(a2) | (bf16_rne(a3) << 16);
                *(uint2*)((char*)Pkb + (size_t)n * 128 + half * 64 + l4 * 8) = pk;
            }
        }
    }
}

// ---------------------------------------------------------------------------
// GAT: one wave handles NPW nodes, lane = h*16+o. Full 32-deep gather
// prefetch (bf16 table: 2 B/lane, 128 B/row). Fixed-max softmax in exp2
// domain. a*lrelu(x) = c1*x + c2*|x| with c1*x folded into fma.
// ---------------------------------------------------------------------------
__global__ __launch_bounds__(256) void gat_kernel(
    const int*            __restrict__ adj,   // [N][DEG]
    const float*          __restrict__ Pq,    // [N][64] fp32
    const unsigned short* __restrict__ Pkb,   // [N][64] bf16
    const float*          __restrict__ aw,    // [64]
    float*                __restrict__ out,   // [64][N]
    int N)
{
    __shared__ float tile[NHO][NPB + 1];

    int lane = threadIdx.x & 63;
    int wv   = threadIdx.x >> 6;

    float a2l = aw[lane] * 1.44269504f;   // fold log2(e)
    float c1  = 0.505f * a2l;
    float c2  = 0.495f * a2l;

    int nbase = blockIdx.x * NPB + wv * NPW;

#pragma unroll 1
    for (int ni = 0; ni < NPW; ni++) {
        int n = nbase + ni;
        float r = 0.f;
        if (n < N) {
            float qv  = Pq[(size_t)n * NHO + lane];
            int jreg  = (lane < DEG) ? adj[(size_t)n * DEG + lane] : -1;
            float c1q = c1 * qv;

            unsigned short raw[DEG];
            int jv[DEG];
#pragma unroll
            for (int t = 0; t < DEG; t++) {
                int j = __builtin_amdgcn_readlane(jreg, t);   // SGPR, uniform
                jv[t] = j;
                const unsigned short* row =
                    Pkb + (((size_t)(j < 0 ? 0 : j)) << 6);
                raw[t] = row[lane];   // coalesced 128B bf16 gather
            }

            float s = 0.f, acc = 0.f;
#pragma unroll
            for (int t = 0; t < DEG; t++) {
                float kv = __uint_as_float((unsigned)raw[t] << 16);  // bf16->f32
                float x  = qv + kv;
                float tt = fmaf(c1, kv, c1q);          // c1*(qv+kv)
                float c  = fmaf(c2, fabsf(x), tt);     // a2*lrelu(x)
                c = dpp_add<0xB1>(c);     // xor 1
                c = dpp_add<0x4E>(c);     // xor 2
                c = dpp_add<0x141>(c);    // xor 4 (half-mirror)
                c = dpp_add<0x140>(c);    // xor 8 (mirror)
                float lg = (jv[t] >= 0) ? c : -1e30f;
                float p  = __builtin_amdgcn_exp2f(lg); // raw v_exp_f32
                s   += p;
                acc  = fmaf(p, kv, acc);
            }
            r = (s > 0.f) ? acc * __builtin_amdgcn_rcpf(s) : 0.f;
        }
        tile[lane][wv * NPW + ni] = r;
    }
    __syncthreads();

    // coalesced write-out: 64 rows x 16 cols, one float4 per thread
    int n0 = blockIdx.x * NPB;
    int l  = threadIdx.x >> 2;
    int c4 = threadIdx.x & 3;
    int nc = n0 + c4 * 4;
    float4 v = make_float4(tile[l][c4 * 4 + 0], tile[l][c4 * 4 + 1],
                           tile[l][c4 * 4 + 2], tile[l][c4 * 4 + 3]);
    if (nc + 3 < N) {
        *(float4*)(out + (size_t)l * N + nc) = v;
    } else {
#pragma unroll
        for (int e = 0; e < 4; e++)
            if (nc + e < N) out[(size_t)l * N + nc + e] = (&v.x)[e];
    }
}

extern "C" void kernel_launch(void* const* d_in, const int* in_sizes, int n_in,
                              void* d_out, int out_size, void* d_ws, size_t ws_size,
                              hipStream_t stream) {
    const int*   adj = (const int*)  d_in[0];
    const float* Q   = (const float*)d_in[1];
    const float* qw  = (const float*)d_in[2];
    const float* kw  = (const float*)d_in[3];
    const float* aw  = (const float*)d_in[4];
    float*       out = (float*)d_out;

    int N = in_sizes[0] / DEG;  // 50000

    float*          Pq  = (float*)d_ws;                             // [N][64] fp32
    unsigned short* Pkb = (unsigned short*)(Pq + (size_t)N * NHO);  // [N][64] bf16

    dim3 pgrid((N + 255) / 256, 4);
    proj_kernel<<<pgrid, 256, 0, stream>>>(Q, qw, kw, Pq, Pkb, N);

    gat_kernel<<<(N + NPB - 1) / NPB, 256, 0, stream>>>(adj, Pq, Pkb, aw, out, N);
}

// Round 6
// 126.980 us; speedup vs baseline: 1.4841x; 1.2096x over previous
//
#include <hip/hip_runtime.h>
#include <math.h>

#define DEG 32
#define NHO 64   // HEADS*OUT_F = 4*16
#define NPW 4    // nodes per wave in gat_kernel
#define NPB 16   // nodes per block (4 waves * NPW)

typedef short  frag8  __attribute__((ext_vector_type(8)));   // 8 bf16 = 4 VGPRs
typedef float  f32x4  __attribute__((ext_vector_type(4)));

// DPP butterfly add within rows of 16 lanes (one attention head).
template <int CTRL>
__device__ __forceinline__ float dpp_add(float v) {
    int t = __builtin_amdgcn_update_dpp(0, __float_as_int(v), CTRL, 0xF, 0xF, true);
    return v + __int_as_float(t);
}

__device__ __forceinline__ unsigned bf16_rne(float f) {
    unsigned u = __float_as_uint(f);
    return (u + 0x7fffu + ((u >> 16) & 1u)) >> 16;
}

// ---------------------------------------------------------------------------
// MFMA projection: one GEMM C[128][N] = W'[128][64] x Q[64][N], where rows
// 0-63 are the query projection (-> Pq fp32 [N][64]) and rows 64-127 the key
// projection (-> Pkb bf16 [N][64]). Per block: 64 nodes (M) x 128 outputs (N)
// x K=64.  A = Q^T staged transposed in LDS as packed-bf16 pairs, row stride
// 33 dwords (bank = (n+d)%32 -> 2-way, free). B = W' bf16 in LDS, same
// stride. Wave w owns m-tile w; 2 k-steps x 8 out-tiles = 16 MFMAs.
// ---------------------------------------------------------------------------
__global__ __launch_bounds__(256) void proj_mfma_kernel(
    const float* __restrict__ Q,
    const float* __restrict__ Wq,
    const float* __restrict__ Wk,
    float* __restrict__ Pq,
    unsigned short* __restrict__ Pkb,
    int N)
{
    __shared__ unsigned qlds[64 * 33];    // [n][k-pair]
    __shared__ unsigned wlds[128 * 33];   // [l][k-pair]

    int t  = threadIdx.x;
    int n0 = blockIdx.x * 64;

    // stage W' = concat(Wq, Wk): 128 rows x 64 k, packed bf16 pairs
    {
        int l    = t >> 1;
        int half = t & 1;
        const float* wr = (l < 64 ? Wq + (size_t)l * 64
                                  : Wk + (size_t)(l - 64) * 64) + half * 32;
#pragma unroll
        for (int r = 0; r < 16; r++) {
            float f0 = wr[2 * r], f1 = wr[2 * r + 1];
            wlds[l * 33 + half * 16 + r] = bf16_rne(f0) | (bf16_rne(f1) << 16);
        }
    }
    // stage Q tile transposed: qlds[n][k>>1]; global reads coalesced per k-row
    {
        int n  = t & 63;
        int gn = n0 + n;
        bool act = (gn < N);
#pragma unroll
        for (int r = 0; r < 8; r++) {
            int dp = (t >> 6) * 8 + r;          // dword-pair index 0..31
            int k  = dp * 2;
            float f0 = act ? Q[(size_t)k * N + gn] : 0.f;
            float f1 = act ? Q[(size_t)(k + 1) * N + gn] : 0.f;
            qlds[n * 33 + dp] = bf16_rne(f0) | (bf16_rne(f1) << 16);
        }
    }
    __syncthreads();

    int lane = t & 63;
    int w    = t >> 6;       // m-tile (16 nodes) per wave
    int li   = lane & 15;
    int quad = lane >> 4;

    f32x4 acc[8];
#pragma unroll
    for (int ot = 0; ot < 8; ot++) acc[ot] = (f32x4){0.f, 0.f, 0.f, 0.f};

#pragma unroll
    for (int ks = 0; ks < 2; ks++) {
        union { unsigned u[4]; frag8 f; } A;
        int abase = (w * 16 + li) * 33 + ks * 16 + quad * 4;
#pragma unroll
        for (int c = 0; c < 4; c++) A.u[c] = qlds[abase + c];
#pragma unroll
        for (int ot = 0; ot < 8; ot++) {
            union { unsigned u[4]; frag8 f; } B;
            int bbase = (ot * 16 + li) * 33 + ks * 16 + quad * 4;
#pragma unroll
            for (int c = 0; c < 4; c++) B.u[c] = wlds[bbase + c];
            acc[ot] = __builtin_amdgcn_mfma_f32_16x16x32_bf16(A.f, B.f, acc[ot],
                                                              0, 0, 0);
        }
    }

    // epilogue: D[node][l]; quad lanes share node -> 64B-contiguous stores
#pragma unroll
    for (int ot = 0; ot < 8; ot++) {
#pragma unroll
        for (int r = 0; r < 4; r++) {
            int node = n0 + w * 16 + quad * 4 + r;
            if (node < N) {
                float v = acc[ot][r];
                if (ot < 4) {
                    Pq[(size_t)node * NHO + ot * 16 + li] = v;
                } else {
                    Pkb[(size_t)node * NHO + (ot - 4) * 16 + li] =
                        (unsigned short)bf16_rne(v);
                }
            }
        }
    }
}

// ---------------------------------------------------------------------------
// GAT: one wave handles NPW nodes, lane = h*16+o. Full 32-deep gather
// prefetch (bf16 table: 2 B/lane, 128 B/row). Fixed-max softmax in exp2
// domain. a*lrelu(x) = c1*x + c2*|x| with c1*x folded into fma.
// ---------------------------------------------------------------------------
__global__ __launch_bounds__(256) void gat_kernel(
    const int*            __restrict__ adj,   // [N][DEG]
    const float*          __restrict__ Pq,    // [N][64] fp32
    const unsigned short* __restrict__ Pkb,   // [N][64] bf16
    const float*          __restrict__ aw,    // [64]
    float*                __restrict__ out,   // [64][N]
    int N)
{
    __shared__ float tile[NHO][NPB + 1];

    int lane = threadIdx.x & 63;
    int wv   = threadIdx.x >> 6;

    float a2l = aw[lane] * 1.44269504f;   // fold log2(e)
    float c1  = 0.505f * a2l;
    float c2  = 0.495f * a2l;

    int nbase = blockIdx.x * NPB + wv * NPW;

#pragma unroll 1
    for (int ni = 0; ni < NPW; ni++) {
        int n = nbase + ni;
        float r = 0.f;
        if (n < N) {
            float qv  = Pq[(size_t)n * NHO + lane];
            int jreg  = (lane < DEG) ? adj[(size_t)n * DEG + lane] : -1;
            float c1q = c1 * qv;

            unsigned short raw[DEG];
            int jv[DEG];
#pragma unroll
            for (int t = 0; t < DEG; t++) {
                int j = __builtin_amdgcn_readlane(jreg, t);   // SGPR, uniform
                jv[t] = j;
                const unsigned short* row =
                    Pkb + (((size_t)(j < 0 ? 0 : j)) << 6);
                raw[t] = row[lane];   // coalesced 128B bf16 gather
            }

            float s = 0.f, acc = 0.f;
#pragma unroll
            for (int t = 0; t < DEG; t++) {
                float kv = __uint_as_float((unsigned)raw[t] << 16);  // bf16->f32
                float x  = qv + kv;
                float tt = fmaf(c1, kv, c1q);          // c1*(qv+kv)
                float c  = fmaf(c2, fabsf(x), tt);     // a2*lrelu(x)
                c = dpp_add<0xB1>(c);     // xor 1
                c = dpp_add<0x4E>(c);     // xor 2
                c = dpp_add<0x141>(c);    // xor 4 (half-mirror)
                c = dpp_add<0x140>(c);    // xor 8 (mirror)
                float lg = (jv[t] >= 0) ? c : -1e30f;
                float p  = __builtin_amdgcn_exp2f(lg); // raw v_exp_f32
                s   += p;
                acc  = fmaf(p, kv, acc);
            }
            r = (s > 0.f) ? acc * __builtin_amdgcn_rcpf(s) : 0.f;
        }
        tile[lane][wv * NPW + ni] = r;
    }
    __syncthreads();

    // coalesced write-out: 64 rows x 16 cols, one float4 per thread
    int n0 = blockIdx.x * NPB;
    int l  = threadIdx.x >> 2;
    int c4 = threadIdx.x & 3;
    int nc = n0 + c4 * 4;
    float4 v = make_float4(tile[l][c4 * 4 + 0], tile[l][c4 * 4 + 1],
                           tile[l][c4 * 4 + 2], tile[l][c4 * 4 + 3]);
    if (nc + 3 < N) {
        *(float4*)(out + (size_t)l * N + nc) = v;
    } else {
#pragma unroll
        for (int e = 0; e < 4; e++)
            if (nc + e < N) out[(size_t)l * N + nc + e] = (&v.x)[e];
    }
}

extern "C" void kernel_launch(void* const* d_in, const int* in_sizes, int n_in,
                              void* d_out, int out_size, void* d_ws, size_t ws_size,
                              hipStream_t stream) {
    const int*   adj = (const int*)  d_in[0];
    const float* Q   = (const float*)d_in[1];
    const float* qw  = (const float*)d_in[2];
    const float* kw  = (const float*)d_in[3];
    const float* aw  = (const float*)d_in[4];
    float*       out = (float*)d_out;

    int N = in_sizes[0] / DEG;  // 50000

    float*          Pq  = (float*)d_ws;                             // [N][64] fp32
    unsigned short* Pkb = (unsigned short*)(Pq + (size_t)N * NHO);  // [N][64] bf16

    proj_mfma_kernel<<<(N + 63) / 64, 256, 0, stream>>>(Q, qw, kw, Pq, Pkb, N);

    gat_kernel<<<(N + NPB - 1) / NPB, 256, 0, stream>>>(adj, Pq, Pkb, aw, out, N);
}

// Round 7
// 111.596 us; speedup vs baseline: 1.6887x; 1.1379x over previous
//
#include <hip/hip_runtime.h>
#include <math.h>

#define DEG 32
#define NHO 64   // HEADS*OUT_F = 4*16
#define NPW 4    // nodes per wave in gat_kernel
#define NPB 16   // nodes per block (4 waves * NPW)

typedef short  frag8  __attribute__((ext_vector_type(8)));   // 8 bf16 = 4 VGPRs
typedef float  f32x4  __attribute__((ext_vector_type(4)));

// DPP butterfly add (used over the 8-lane o-group: xor1, xor2, then
// row_half_mirror == xor4 once bits 0-1 are uniform).
template <int CTRL>
__device__ __forceinline__ float dpp_add(float v) {
    int t = __builtin_amdgcn_update_dpp(0, __float_as_int(v), CTRL, 0xF, 0xF, true);
    return v + __int_as_float(t);
}

__device__ __forceinline__ unsigned bf16_rne(float f) {
    unsigned u = __float_as_uint(f);
    return (u + 0x7fffu + ((u >> 16) & 1u)) >> 16;
}

// ---------------------------------------------------------------------------
// MFMA projection (unchanged from R6): C[128][N] = W'[128][64] x Q[64][N];
// rows 0-63 -> Pq fp32 [N][64], rows 64-127 -> Pkb bf16 [N][64].
// ---------------------------------------------------------------------------
__global__ __launch_bounds__(256) void proj_mfma_kernel(
    const float* __restrict__ Q,
    const float* __restrict__ Wq,
    const float* __restrict__ Wk,
    float* __restrict__ Pq,
    unsigned short* __restrict__ Pkb,
    int N)
{
    __shared__ unsigned qlds[64 * 33];    // [n][k-pair]
    __shared__ unsigned wlds[128 * 33];   // [l][k-pair]

    int t  = threadIdx.x;
    int n0 = blockIdx.x * 64;

    {
        int l    = t >> 1;
        int half = t & 1;
        const float* wr = (l < 64 ? Wq + (size_t)l * 64
                                  : Wk + (size_t)(l - 64) * 64) + half * 32;
#pragma unroll
        for (int r = 0; r < 16; r++) {
            float f0 = wr[2 * r], f1 = wr[2 * r + 1];
            wlds[l * 33 + half * 16 + r] = bf16_rne(f0) | (bf16_rne(f1) << 16);
        }
    }
    {
        int n  = t & 63;
        int gn = n0 + n;
        bool act = (gn < N);
#pragma unroll
        for (int r = 0; r < 8; r++) {
            int dp = (t >> 6) * 8 + r;
            int k  = dp * 2;
            float f0 = act ? Q[(size_t)k * N + gn] : 0.f;
            float f1 = act ? Q[(size_t)(k + 1) * N + gn] : 0.f;
            qlds[n * 33 + dp] = bf16_rne(f0) | (bf16_rne(f1) << 16);
        }
    }
    __syncthreads();

    int lane = t & 63;
    int w    = t >> 6;
    int li   = lane & 15;
    int quad = lane >> 4;

    f32x4 acc[8];
#pragma unroll
    for (int ot = 0; ot < 8; ot++) acc[ot] = (f32x4){0.f, 0.f, 0.f, 0.f};

#pragma unroll
    for (int ks = 0; ks < 2; ks++) {
        union { unsigned u[4]; frag8 f; } A;
        int abase = (w * 16 + li) * 33 + ks * 16 + quad * 4;
#pragma unroll
        for (int c = 0; c < 4; c++) A.u[c] = qlds[abase + c];
#pragma unroll
        for (int ot = 0; ot < 8; ot++) {
            union { unsigned u[4]; frag8 f; } B;
            int bbase = (ot * 16 + li) * 33 + ks * 16 + quad * 4;
#pragma unroll
            for (int c = 0; c < 4; c++) B.u[c] = wlds[bbase + c];
            acc[ot] = __builtin_amdgcn_mfma_f32_16x16x32_bf16(A.f, B.f, acc[ot],
                                                              0, 0, 0);
        }
    }

#pragma unroll
    for (int ot = 0; ot < 8; ot++) {
#pragma unroll
        for (int r = 0; r < 4; r++) {
            int node = n0 + w * 16 + quad * 4 + r;
            if (node < N) {
                float v = acc[ot][r];
                if (ot < 4) {
                    Pq[(size_t)node * NHO + ot * 16 + li] = v;
                } else {
                    Pkb[(size_t)node * NHO + (ot - 4) * 16 + li] =
                        (unsigned short)bf16_rne(v);
                }
            }
        }
    }
}

// ---------------------------------------------------------------------------
// GAT, 2-edges-per-iteration layout. Lane l: slot = l>>5 (edge slot),
// sl = l&31 -> ho pair {2sl, 2sl+1} (head h = sl>>3, o-group og = sl&7).
// Per iteration t (16 per node): slot0 handles edge t, slot1 edge t+16.
// One global_load_dword per lane covers two full 128 B bf16 rows per instr.
// o-reduction: in-lane pair add folded into the fma chain + 3 DPP steps over
// the 8-lane o-group. exp/cndmask/s-add issue once per 2 edges.
// ---------------------------------------------------------------------------
__global__ __launch_bounds__(256) void gat_kernel(
    const int*            __restrict__ adj,   // [N][DEG]
    const float*          __restrict__ Pq,    // [N][64] fp32
    const unsigned short* __restrict__ Pkb,   // [N][64] bf16
    const float*          __restrict__ aw,    // [64]
    float*                __restrict__ out,   // [64][N]
    int N)
{
    __shared__ float tile[NHO][NPB + 1];

    int l    = threadIdx.x & 63;
    int wv   = threadIdx.x >> 6;
    int sl   = l & 31;
    int slot = l >> 5;

    const unsigned* Pk32 = (const unsigned*)Pkb;   // dword = one ho-pair

    float2 awp = *(const float2*)(aw + 2 * sl);
    const float L2E = 1.44269504f;
    float c1_0 = 0.505f * L2E * awp.x, c2_0 = 0.495f * L2E * awp.x;
    float c1_1 = 0.505f * L2E * awp.y, c2_1 = 0.495f * L2E * awp.y;

    int bprm_it0 = slot * 64;          // byte index of this slot's first edge
    int bprm_xor = (l ^ 32) * 4;       // cross-slot partner for combines

    int nbase = blockIdx.x * NPB + wv * NPW;

#pragma unroll 1
    for (int ni = 0; ni < NPW; ni++) {
        int n = nbase + ni;
        if (n < N) {
            float2 qp = *(const float2*)(Pq + (size_t)n * NHO + 2 * sl);
            int adjA  = adj[(size_t)n * DEG + sl];    // lane sl holds edge sl
            float c1q = fmaf(c1_1, qp.y, c1_0 * qp.x);

            int      jv[16];
            unsigned kvr[16];
#pragma unroll
            for (int t = 0; t < 16; t++) {
                int j = __builtin_amdgcn_ds_bpermute(bprm_it0 + t * 4, adjA);
                jv[t] = j;
                unsigned off = (((unsigned)(j < 0 ? 0 : j)) << 5) + sl;
                kvr[t] = Pk32[off];   // 2 rows x 128B per instruction
            }

            float s = 0.f, a0 = 0.f, a1 = 0.f;
#pragma unroll
            for (int t = 0; t < 16; t++) {
                float kv0 = __uint_as_float(kvr[t] << 16);
                float kv1 = __uint_as_float(kvr[t] & 0xffff0000u);
                float x0  = qp.x + kv0;
                float x1  = qp.y + kv1;
                float c   = fmaf(c1_0, kv0, c1q);
                c = fmaf(c1_1, kv1, c);
                c = fmaf(c2_0, fabsf(x0), c);
                c = fmaf(c2_1, fabsf(x1), c);
                c = dpp_add<0xB1>(c);     // xor 1
                c = dpp_add<0x4E>(c);     // xor 2
                c = dpp_add<0x141>(c);    // half-mirror == xor 4 here
                float p = __builtin_amdgcn_exp2f(c);
                p = (jv[t] >= 0) ? p : 0.f;
                s += p;
                a0 = fmaf(p, kv0, a0);
                a1 = fmaf(p, kv1, a1);
            }

            // combine the two edge-slots (lanes l and l^32)
            s  += __int_as_float(__builtin_amdgcn_ds_bpermute(bprm_xor, __float_as_int(s)));
            a0 += __int_as_float(__builtin_amdgcn_ds_bpermute(bprm_xor, __float_as_int(a0)));
            a1 += __int_as_float(__builtin_amdgcn_ds_bpermute(bprm_xor, __float_as_int(a1)));

            float rs = (s > 0.f) ? __builtin_amdgcn_rcpf(s) : 0.f;
            if (slot == 0) {
                int col = wv * NPW + ni;
                tile[2 * sl + 0][col] = a0 * rs;
                tile[2 * sl + 1][col] = a1 * rs;
            }
        }
    }
    __syncthreads();

    // coalesced write-out: 64 rows x 16 cols, one float4 per thread
    int n0 = blockIdx.x * NPB;
    int lr = threadIdx.x >> 2;
    int c4 = threadIdx.x & 3;
    int nc = n0 + c4 * 4;
    float4 v = make_float4(tile[lr][c4 * 4 + 0], tile[lr][c4 * 4 + 1],
                           tile[lr][c4 * 4 + 2], tile[lr][c4 * 4 + 3]);
    if (nc + 3 < N) {
        *(float4*)(out + (size_t)lr * N + nc) = v;
    } else {
#pragma unroll
        for (int e = 0; e < 4; e++)
            if (nc + e < N) out[(size_t)lr * N + nc + e] = (&v.x)[e];
    }
}

extern "C" void kernel_launch(void* const* d_in, const int* in_sizes, int n_in,
                              void* d_out, int out_size, void* d_ws, size_t ws_size,
                              hipStream_t stream) {
    const int*   adj = (const int*)  d_in[0];
    const float* Q   = (const float*)d_in[1];
    const float* qw  = (const float*)d_in[2];
    const float* kw  = (const float*)d_in[3];
    const float* aw  = (const float*)d_in[4];
    float*       out = (float*)d_out;

    int N = in_sizes[0] / DEG;  // 50000

    float*          Pq  = (float*)d_ws;                             // [N][64] fp32
    unsigned short* Pkb = (unsigned short*)(Pq + (size_t)N * NHO);  // [N][64] bf16

    proj_mfma_kernel<<<(N + 63) / 64, 256, 0, stream>>>(Q, qw, kw, Pq, Pkb, N);

    gat_kernel<<<(N + NPB - 1) / NPB, 256, 0, stream>>>(adj, Pq, Pkb, aw, out, N);
}

// Round 8
// 107.615 us; speedup vs baseline: 1.7512x; 1.0370x over previous
//
#include <hip/hip_runtime.h>
#include <math.h>

#define DEG 32
#define NHO 64   // HEADS*OUT_F = 4*16
#define NPW 4    // nodes per wave in gat_kernel
#define NPB 16   // nodes per block (4 waves * NPW)

typedef short  frag8  __attribute__((ext_vector_type(8)));   // 8 bf16 = 4 VGPRs
typedef float  f32x4  __attribute__((ext_vector_type(4)));

// DPP butterfly add within quads (4 lanes): xor1 = quad_perm[1,0,3,2]=0xB1,
// xor2 = quad_perm[2,3,0,1]=0x4E.
template <int CTRL>
__device__ __forceinline__ float dpp_add(float v) {
    int t = __builtin_amdgcn_update_dpp(0, __float_as_int(v), CTRL, 0xF, 0xF, true);
    return v + __int_as_float(t);
}

__device__ __forceinline__ unsigned bf16_rne(float f) {
    unsigned u = __float_as_uint(f);
    return (u + 0x7fffu + ((u >> 16) & 1u)) >> 16;
}

// ---------------------------------------------------------------------------
// MFMA projection: C[128][N] = W'[128][64] x Q[64][N]; rows 0-63 -> Pqb,
// rows 64-127 -> Pkb, both bf16 [N][64] (128 B rows).
// ---------------------------------------------------------------------------
__global__ __launch_bounds__(256) void proj_mfma_kernel(
    const float* __restrict__ Q,
    const float* __restrict__ Wq,
    const float* __restrict__ Wk,
    unsigned short* __restrict__ Pqb,
    unsigned short* __restrict__ Pkb,
    int N)
{
    __shared__ unsigned qlds[64 * 33];    // [n][k-pair]
    __shared__ unsigned wlds[128 * 33];   // [l][k-pair]

    int t  = threadIdx.x;
    int n0 = blockIdx.x * 64;

    {
        int l    = t >> 1;
        int half = t & 1;
        const float* wr = (l < 64 ? Wq + (size_t)l * 64
                                  : Wk + (size_t)(l - 64) * 64) + half * 32;
#pragma unroll
        for (int r = 0; r < 16; r++) {
            float f0 = wr[2 * r], f1 = wr[2 * r + 1];
            wlds[l * 33 + half * 16 + r] = bf16_rne(f0) | (bf16_rne(f1) << 16);
        }
    }
    {
        int n  = t & 63;
        int gn = n0 + n;
        bool act = (gn < N);
#pragma unroll
        for (int r = 0; r < 8; r++) {
            int dp = (t >> 6) * 8 + r;
            int k  = dp * 2;
            float f0 = act ? Q[(size_t)k * N + gn] : 0.f;
            float f1 = act ? Q[(size_t)(k + 1) * N + gn] : 0.f;
            qlds[n * 33 + dp] = bf16_rne(f0) | (bf16_rne(f1) << 16);
        }
    }
    __syncthreads();

    int lane = t & 63;
    int w    = t >> 6;
    int li   = lane & 15;
    int quad = lane >> 4;

    f32x4 acc[8];
#pragma unroll
    for (int ot = 0; ot < 8; ot++) acc[ot] = (f32x4){0.f, 0.f, 0.f, 0.f};

#pragma unroll
    for (int ks = 0; ks < 2; ks++) {
        union { unsigned u[4]; frag8 f; } A;
        int abase = (w * 16 + li) * 33 + ks * 16 + quad * 4;
#pragma unroll
        for (int c = 0; c < 4; c++) A.u[c] = qlds[abase + c];
#pragma unroll
        for (int ot = 0; ot < 8; ot++) {
            union { unsigned u[4]; frag8 f; } B;
            int bbase = (ot * 16 + li) * 33 + ks * 16 + quad * 4;
#pragma unroll
            for (int c = 0; c < 4; c++) B.u[c] = wlds[bbase + c];
            acc[ot] = __builtin_amdgcn_mfma_f32_16x16x32_bf16(A.f, B.f, acc[ot],
                                                              0, 0, 0);
        }
    }

#pragma unroll
    for (int ot = 0; ot < 8; ot++) {
#pragma unroll
        for (int r = 0; r < 4; r++) {
            int node = n0 + w * 16 + quad * 4 + r;
            if (node < N) {
                unsigned short v = (unsigned short)bf16_rne(acc[ot][r]);
                if (ot < 4)
                    Pqb[(size_t)node * NHO + ot * 16 + li] = v;
                else
                    Pkb[(size_t)node * NHO + (ot - 4) * 16 + li] = v;
            }
        }
    }
}

// ---------------------------------------------------------------------------
// GAT, 4-edges-per-iteration. Lane l: slot = l>>4 (edge slot), sl = l&15 ->
// ho-quad {4sl..4sl+3} (head = sl>>2). Per iteration t (8 per node), slot s
// handles edge s*8+t: one uint2 load covers 4 bf16 -> 4 slots x 16 lanes =
// four full 128 B rows per load instruction. o-reduction: 4 in-lane fma +
// 2 DPP quad steps. exp/sel/s-add amortized over 4 edges. Cross-slot
// combine: xor16/xor32 butterfly on (s, a0..a3) once per node.
// ---------------------------------------------------------------------------
__global__ __launch_bounds__(256) void gat_kernel(
    const int*            __restrict__ adj,   // [N][DEG]
    const unsigned short* __restrict__ Pqb,   // [N][64] bf16
    const unsigned short* __restrict__ Pkb,   // [N][64] bf16
    const float*          __restrict__ aw,    // [64]
    float*                __restrict__ out,   // [64][N]
    int N)
{
    __shared__ float tile[NHO][NPB + 1];

    int l    = threadIdx.x & 63;
    int wv   = threadIdx.x >> 6;
    int sl   = l & 15;
    int slot = l >> 4;

    const uint2* Pk64 = (const uint2*)Pkb;   // 16 uint2 per row
    const uint2* Pq64 = (const uint2*)Pqb;

    float4 awq = *(const float4*)(aw + 4 * sl);
    const float L2E = 1.44269504f;
    float c1_0 = 0.505f * L2E * awq.x, c2_0 = 0.495f * L2E * awq.x;
    float c1_1 = 0.505f * L2E * awq.y, c2_1 = 0.495f * L2E * awq.y;
    float c1_2 = 0.505f * L2E * awq.z, c2_2 = 0.495f * L2E * awq.z;
    float c1_3 = 0.505f * L2E * awq.w, c2_3 = 0.495f * L2E * awq.w;

    int bprm_x16 = (l ^ 16) * 4;
    int bprm_x32 = (l ^ 32) * 4;

    int nbase = blockIdx.x * NPB + wv * NPW;

#pragma unroll 1
    for (int ni = 0; ni < NPW; ni++) {
        int n = nbase + ni;
        if (n < N) {
            uint2 qraw = Pq64[(size_t)n * 16 + sl];
            float qp0 = __uint_as_float(qraw.x << 16);
            float qp1 = __uint_as_float(qraw.x & 0xffff0000u);
            float qp2 = __uint_as_float(qraw.y << 16);
            float qp3 = __uint_as_float(qraw.y & 0xffff0000u);
            int adjA  = adj[(size_t)n * DEG + (l & 31)];  // lane e holds edge e

            float c1q = c1_0 * qp0;
            c1q = fmaf(c1_1, qp1, c1q);
            c1q = fmaf(c1_2, qp2, c1q);
            c1q = fmaf(c1_3, qp3, c1q);

            int   jv[8];
            uint2 kvr[8];
#pragma unroll
            for (int t = 0; t < 8; t++) {
                int j = __builtin_amdgcn_ds_bpermute((slot * 8 + t) * 4, adjA);
                jv[t] = j;
                kvr[t] = Pk64[(size_t)(j < 0 ? 0 : j) * 16 + sl];
            }

            float s = 0.f, a0 = 0.f, a1 = 0.f, a2 = 0.f, a3 = 0.f;
#pragma unroll
            for (int t = 0; t < 8; t++) {
                float kv0 = __uint_as_float(kvr[t].x << 16);
                float kv1 = __uint_as_float(kvr[t].x & 0xffff0000u);
                float kv2 = __uint_as_float(kvr[t].y << 16);
                float kv3 = __uint_as_float(kvr[t].y & 0xffff0000u);
                float x0 = qp0 + kv0, x1 = qp1 + kv1;
                float x2 = qp2 + kv2, x3 = qp3 + kv3;
                float c = fmaf(c1_0, kv0, c1q);
                c = fmaf(c1_1, kv1, c);
                c = fmaf(c1_2, kv2, c);
                c = fmaf(c1_3, kv3, c);
                c = fmaf(c2_0, fabsf(x0), c);
                c = fmaf(c2_1, fabsf(x1), c);
                c = fmaf(c2_2, fabsf(x2), c);
                c = fmaf(c2_3, fabsf(x3), c);
                c = dpp_add<0xB1>(c);     // xor 1 (within quad)
                c = dpp_add<0x4E>(c);     // xor 2 (within quad)
                float p = __builtin_amdgcn_exp2f(c);
                p = (jv[t] >= 0) ? p : 0.f;
                s += p;
                a0 = fmaf(p, kv0, a0);
                a1 = fmaf(p, kv1, a1);
                a2 = fmaf(p, kv2, a2);
                a3 = fmaf(p, kv3, a3);
            }

            // butterfly-combine the 4 edge slots (xor16 then xor32)
            s  += __int_as_float(__builtin_amdgcn_ds_bpermute(bprm_x16, __float_as_int(s)));
            a0 += __int_as_float(__builtin_amdgcn_ds_bpermute(bprm_x16, __float_as_int(a0)));
            a1 += __int_as_float(__builtin_amdgcn_ds_bpermute(bprm_x16, __float_as_int(a1)));
            a2 += __int_as_float(__builtin_amdgcn_ds_bpermute(bprm_x16, __float_as_int(a2)));
            a3 += __int_as_float(__builtin_amdgcn_ds_bpermute(bprm_x16, __float_as_int(a3)));
            s  += __int_as_float(__builtin_amdgcn_ds_bpermute(bprm_x32, __float_as_int(s)));
            a0 += __int_as_float(__builtin_amdgcn_ds_bpermute(bprm_x32, __float_as_int(a0)));
            a1 += __int_as_float(__builtin_amdgcn_ds_bpermute(bprm_x32, __float_as_int(a1)));
            a2 += __int_as_float(__builtin_amdgcn_ds_bpermute(bprm_x32, __float_as_int(a2)));
            a3 += __int_as_float(__builtin_amdgcn_ds_bpermute(bprm_x32, __float_as_int(a3)));

            float rs = (s > 0.f) ? __builtin_amdgcn_rcpf(s) : 0.f;
            if (slot == 0) {
                int col = wv * NPW + ni;
                tile[4 * sl + 0][col] = a0 * rs;
                tile[4 * sl + 1][col] = a1 * rs;
                tile[4 * sl + 2][col] = a2 * rs;
                tile[4 * sl + 3][col] = a3 * rs;
            }
        }
    }
    __syncthreads();

    // coalesced write-out: 64 rows x 16 cols, one float4 per thread
    int n0 = blockIdx.x * NPB;
    int lr = threadIdx.x >> 2;
    int c4 = threadIdx.x & 3;
    int nc = n0 + c4 * 4;
    float4 v = make_float4(tile[lr][c4 * 4 + 0], tile[lr][c4 * 4 + 1],
                           tile[lr][c4 * 4 + 2], tile[lr][c4 * 4 + 3]);
    if (nc + 3 < N) {
        *(float4*)(out + (size_t)lr * N + nc) = v;
    } else {
#pragma unroll
        for (int e = 0; e < 4; e++)
            if (nc + e < N) out[(size_t)lr * N + nc + e] = (&v.x)[e];
    }
}

extern "C" void kernel_launch(void* const* d_in, const int* in_sizes, int n_in,
                              void* d_out, int out_size, void* d_ws, size_t ws_size,
                              hipStream_t stream) {
    const int*   adj = (const int*)  d_in[0];
    const float* Q   = (const float*)d_in[1];
    const float* qw  = (const float*)d_in[2];
    const float* kw  = (const float*)d_in[3];
    const float* aw  = (const float*)d_in[4];
    float*       out = (float*)d_out;

    int N = in_sizes[0] / DEG;  // 50000

    unsigned short* Pqb = (unsigned short*)d_ws;         // [N][64] bf16
    unsigned short* Pkb = Pqb + (size_t)N * NHO;         // [N][64] bf16

    proj_mfma_kernel<<<(N + 63) / 64, 256, 0, stream>>>(Q, qw, kw, Pqb, Pkb, N);

    gat_kernel<<<(N + NPB - 1) / NPB, 256, 0, stream>>>(adj, Pqb, Pkb, aw, out, N);
}